// Round 1
// baseline (293.316 us; speedup 1.0000x reference)
//
#include <hip/hip_runtime.h>

// C51 categorical projection.
// prob_next: [B,51] f32, r: [B,1] f32, done: [B,1] f32 -> out: [B,51] f32
// Per row: atom_j = clip(r + 0.9*(1-done)*support_j, -40, 80);
//          b = (atom_j + 40)/2.4; l=floor(b); u=ceil(b);
//          out[l] += (u + (l==u) - b)*p_j; out[u] += (b-l)*p_j;
// Bit-exactness vs numpy: support in f64 then cast (np.linspace), all f32 ops
// via __f*_rn intrinsics to forbid FMA contraction / rcp division (a 1-ulp
// drift in b near an integer flips a bin -> absmax ~p > threshold).

#define ATOMS 51
#define RPB 64                  // rows per block
#define THREADS 256
#define ELEMS (RPB * ATOMS)     // 3264
#define NVEC (ELEMS / 4)        // 816 float4s; 64*51*4B = 13056B block slice, 16B-aligned

__global__ __launch_bounds__(THREADS) void c51_project(
    const float* __restrict__ prob,
    const float* __restrict__ r,
    const float* __restrict__ done,
    float* __restrict__ out,
    int nrows)
{
    __shared__ float s_acc[ELEMS];
    __shared__ float s_r[RPB];
    __shared__ float s_c[RPB];
    __shared__ float s_sup[ATOMS];

    const int tid = threadIdx.x;
    const long long row0 = (long long)blockIdx.x * RPB;
    const int rows_here = (int)min((long long)RPB, (long long)nrows - row0);

    if (tid < RPB && tid < rows_here) {
        s_r[tid] = r[row0 + tid];
        // GAMMA*(1-done): done is exactly 0.0 or 1.0 -> coef exactly 0.9f or 0.0f
        s_c[tid] = __fmul_rn(0.9f, __fsub_rn(1.0f, done[row0 + tid]));
    }
    if (tid < ATOMS) {
        // np.linspace(-40, 80, 51, f32): computed in f64, cast to f32
        s_sup[tid] = (float)(-40.0 + (double)tid * 2.4);
    }
    for (int i = tid; i < ELEMS; i += THREADS) s_acc[i] = 0.0f;
    __syncthreads();

    if (rows_here == RPB) {
        // ---- fast path: full block of 64 rows, vectorized ----
        const float4* src = reinterpret_cast<const float4*>(prob + (size_t)row0 * ATOMS);
        for (int i = tid; i < NVEC; i += THREADS) {
            float4 v = src[i];
            const int e0 = i * 4;
            float pv0 = v.x, pv1 = v.y, pv2 = v.z, pv3 = v.w;
            float pvs[4] = {pv0, pv1, pv2, pv3};
            #pragma unroll
            for (int k = 0; k < 4; ++k) {
                const int e = e0 + k;
                const unsigned row = (unsigned)e / ATOMS;   // magic-mul
                const int j = e - (int)row * ATOMS;
                float atom = __fadd_rn(s_r[row], __fmul_rn(s_c[row], s_sup[j]));
                atom = fminf(fmaxf(atom, -40.0f), 80.0f);
                const float b = __fdiv_rn(__fsub_rn(atom, -40.0f), 2.4f);
                const float l = floorf(b);
                const float u = ceilf(b);
                const float corr = (l == u) ? 1.0f : 0.0f;
                const float dml = __fmul_rn(__fsub_rn(__fadd_rn(u, corr), b), pvs[k]);
                const float dmu = __fmul_rn(__fsub_rn(b, l), pvs[k]);
                const int base = (int)row * ATOMS;
                atomicAdd(&s_acc[base + (int)l], dml);
                atomicAdd(&s_acc[base + (int)u], dmu);
            }
        }
        __syncthreads();
        float4* dst = reinterpret_cast<float4*>(out + (size_t)row0 * ATOMS);
        const float4* accv = reinterpret_cast<const float4*>(s_acc);
        for (int i = tid; i < NVEC; i += THREADS) dst[i] = accv[i];
    } else {
        // ---- tail path (scalar, guarded) ----
        const int n_e = rows_here * ATOMS;
        const float* src = prob + (size_t)row0 * ATOMS;
        for (int e = tid; e < n_e; e += THREADS) {
            const unsigned row = (unsigned)e / ATOMS;
            const int j = e - (int)row * ATOMS;
            const float pv = src[e];
            float atom = __fadd_rn(s_r[row], __fmul_rn(s_c[row], s_sup[j]));
            atom = fminf(fmaxf(atom, -40.0f), 80.0f);
            const float b = __fdiv_rn(__fsub_rn(atom, -40.0f), 2.4f);
            const float l = floorf(b);
            const float u = ceilf(b);
            const float corr = (l == u) ? 1.0f : 0.0f;
            const float dml = __fmul_rn(__fsub_rn(__fadd_rn(u, corr), b), pv);
            const float dmu = __fmul_rn(__fsub_rn(b, l), pv);
            const int base = (int)row * ATOMS;
            atomicAdd(&s_acc[base + (int)l], dml);
            atomicAdd(&s_acc[base + (int)u], dmu);
        }
        __syncthreads();
        float* dst = out + (size_t)row0 * ATOMS;
        for (int e = tid; e < n_e; e += THREADS) dst[e] = s_acc[e];
    }
}

extern "C" void kernel_launch(void* const* d_in, const int* in_sizes, int n_in,
                              void* d_out, int out_size, void* d_ws, size_t ws_size,
                              hipStream_t stream) {
    const float* prob = (const float*)d_in[0];
    const float* r    = (const float*)d_in[1];
    const float* done = (const float*)d_in[2];
    float* out = (float*)d_out;
    const int B = in_sizes[1];                 // r has B elements
    const int grid = (B + RPB - 1) / RPB;
    c51_project<<<dim3(grid), dim3(THREADS), 0, stream>>>(prob, r, done, out, B);
}

// Round 2
// 49.149 us; speedup vs baseline: 5.9679x; 5.9679x over previous
//
#include <hip/hip_runtime.h>

// C51 categorical projection, scatter-free streaming formulation.
//
// Per row: b_j = clamp((r+40)/2.4 + c*j - (40/2.4)*c, 0, 50), c = 0.9*(1-done).
// b_j is monotone nondecreasing in j with step c <= 0.9 < 1, so l_j = floor(b_j)
// advances by 0 or 1 per step -> each output bin is a contiguous-j reduction.
// Two running accumulators (vcur for bin `cur`, vnext for bin `cur+1`) emit each
// bin exactly once. No atomics (R1 showed f32 LDS atomicAdd = CAS loop + same-
// address hotspot at clipped bins 0/50 -> 293us latency-bound).
//
// Numerics: the projection is CONTINUOUS in b (the (l==u) correction closes the
// gap at integer b), so ulp-level drift from fma/reciprocal perturbs output by
// ~1e-7*p << 2e-2 threshold. Exact-rounding replication not required.

#define ATOMS 51
#define RPB   64                          // rows per block == threads (1 wave)
#define THREADS 64
#define TILE_FLOATS (RPB * ATOMS)         // 3264 floats = 13056 B
#define TILE_VECS   (TILE_FLOATS / 4)     // 816 float4
#define VEC_ITERS   ((TILE_VECS + THREADS - 1) / THREADS)  // 13 (last: 48 lanes)

__global__ __launch_bounds__(THREADS) void c51_project(
    const float* __restrict__ prob,
    const float* __restrict__ rin,
    const float* __restrict__ done,
    float* __restrict__ out,
    int nrows)
{
    __shared__ __align__(16) float s_buf[TILE_FLOATS];
    const int t = threadIdx.x;
    const long long row0 = (long long)blockIdx.x * RPB;
    const int rows_here = (int)min((long long)RPB, (long long)nrows - row0);
    const bool full = (rows_here == RPB);

    // ---- stage prob tile into LDS, coalesced float4 ----
    if (full) {
        const float4* gsrc = reinterpret_cast<const float4*>(prob + (size_t)row0 * ATOMS);
        float4* sv = reinterpret_cast<float4*>(s_buf);
        #pragma unroll
        for (int i = 0; i < VEC_ITERS; ++i) {
            const int v = i * THREADS + t;
            if (v < TILE_VECS) sv[v] = gsrc[v];
        }
    } else {
        const int n_e = rows_here * ATOMS;
        const float* gsrc = prob + (size_t)row0 * ATOMS;
        for (int e = t; e < n_e; e += THREADS) s_buf[e] = gsrc[e];
    }
    __syncthreads();

    // ---- one thread per row: read row to regs, stream bins back into s_buf ----
    if (t < rows_here) {
        const float rr = rin[row0 + t];
        const float c  = 0.9f * (1.0f - done[row0 + t]);   // exactly 0.9 or 0.0
        // b_j = clamp(base + c*j, 0, 50)
        const float base = fmaf(-16.66666667f, c, (rr + 40.0f) * (1.0f / 2.4f));
        const int ib = t * ATOMS;

        // read entire row into registers (static indices only; rule #20)
        float p[ATOMS];
        #pragma unroll
        for (int j = 0; j < ATOMS; ++j) p[j] = s_buf[ib + j];

        // zero own output slice (overwrites own input slice - no cross-thread use)
        #pragma unroll
        for (int i = 0; i < ATOMS; ++i) s_buf[ib + i] = 0.0f;

        int   cur   = (int)floorf(fminf(fmaxf(base, 0.0f), 50.0f));  // l_0
        float vcur  = 0.0f, vnext = 0.0f;
        #pragma unroll
        for (int j = 0; j < ATOMS; ++j) {
            float b = fmaf(c, (float)j, base);
            b = fminf(fmaxf(b, 0.0f), 50.0f);
            const float lf = floorf(b);
            const float f  = b - lf;            // frac in [0,1)
            const int  li  = (int)lf;
            while (li > cur) {                  // advance (normally 0 or 1 step)
                s_buf[ib + cur] = vcur;
                vcur = vnext; vnext = 0.0f; ++cur;
            }
            vcur  = fmaf(1.0f - f, p[j], vcur); // mass to bin l  (= p when f==0)
            vnext = fmaf(f,        p[j], vnext);// mass to bin l+1 (0 when f==0)
        }
        s_buf[ib + cur] = vcur;
        if (cur < ATOMS - 1) s_buf[ib + cur + 1] = vnext;
    }
    __syncthreads();

    // ---- coalesced float4 writeout ----
    if (full) {
        float4* dst = reinterpret_cast<float4*>(out + (size_t)row0 * ATOMS);
        const float4* sv = reinterpret_cast<const float4*>(s_buf);
        #pragma unroll
        for (int i = 0; i < VEC_ITERS; ++i) {
            const int v = i * THREADS + t;
            if (v < TILE_VECS) dst[v] = sv[v];
        }
    } else {
        const int n_e = rows_here * ATOMS;
        float* dst = out + (size_t)row0 * ATOMS;
        for (int e = t; e < n_e; e += THREADS) dst[e] = s_buf[e];
    }
}

extern "C" void kernel_launch(void* const* d_in, const int* in_sizes, int n_in,
                              void* d_out, int out_size, void* d_ws, size_t ws_size,
                              hipStream_t stream) {
    const float* prob = (const float*)d_in[0];
    const float* r    = (const float*)d_in[1];
    const float* done = (const float*)d_in[2];
    float* outp = (float*)d_out;
    const int B = in_sizes[1];               // r: [B,1]
    const int grid = (B + RPB - 1) / RPB;
    c51_project<<<dim3(grid), dim3(THREADS), 0, stream>>>(prob, r, done, outp, B);
}

// Round 3
// 47.389 us; speedup vs baseline: 6.1895x; 1.0371x over previous
//
#include <hip/hip_runtime.h>
#include <stdint.h>

// C51 categorical projection — pipelined persistent-block version.
//
// R2 structure (scatter-free per-row streaming, 1 wave = 64 rows) kept.
// New: grid-stride persistent blocks with LDS double-buffer; tile k+1 staged
// via __builtin_amdgcn_global_load_lds (16B) BEFORE computing tile k, with a
// counted `s_waitcnt vmcnt(15)` (13 stage loads + 2 r/done prefetch loads stay
// in flight) instead of a full drain — the cp.async-style pipeline (T3/T4).
// Single-wave blocks: no s_barrier needed anywhere in the main loop.
//
// vmcnt FIFO accounting (steady state, program order per iter k):
//   outstanding at wait: [stage_k(13), rd_k(2), stores_{k-1}(13), stage_{k+1}(13), rd_{k+1}(2)]
//   s_waitcnt vmcnt(15) drains everything except the 15 newest
//   => stage_k + rd_k + stores_{k-1} complete, next tile's loads still flying.

#define ATOMS 51
#define RPB   64
#define THREADS 64
#define TILE_FLOATS (RPB * ATOMS)          // 3264
#define TILE_VECS   (TILE_FLOATS / 4)      // 816
#define STAGE_ITERS ((TILE_VECS + THREADS - 1) / THREADS)  // 13
#define GRID_MAX 1536                      // 256 CU x 6 blocks (LDS: 26112B -> 6/CU)

typedef const __attribute__((address_space(1))) void gvoid_t;
typedef __attribute__((address_space(3))) void lvoid_t;

__device__ __forceinline__ void stage_tile(const float* gbase, float* lbase, int t) {
    #pragma unroll
    for (int i = 0; i < STAGE_ITERS; ++i) {
        const int v = i * THREADS + t;
        if (v < TILE_VECS) {
            // LDS dest: wave-uniform base (i*1024B) + lane*16 (HW); global src per-lane.
            __builtin_amdgcn_global_load_lds((gvoid_t*)(gbase + (size_t)v * 4),
                                             (lvoid_t*)(lbase + i * THREADS * 4),
                                             16, 0, 0);
        }
    }
}

__device__ __forceinline__ void compute_row(float* sb, int t, float rr, float dn) {
    const float c = 0.9f * (1.0f - dn);                      // exactly 0.9 or 0.0
    const float base = fmaf(-16.66666667f, c, (rr + 40.0f) * (1.0f / 2.4f));
    const int ib = t * ATOMS;

    float p[ATOMS];
    #pragma unroll
    for (int j = 0; j < ATOMS; ++j) p[j] = sb[ib + j];
    #pragma unroll
    for (int j = 0; j < ATOMS; ++j) sb[ib + j] = 0.0f;

    int   cur  = (int)floorf(fminf(fmaxf(base, 0.0f), 50.0f));
    float vcur = 0.0f, vnext = 0.0f;
    #pragma unroll
    for (int j = 0; j < ATOMS; ++j) {
        float b = fmaf(c, (float)j, base);
        b = fminf(fmaxf(b, 0.0f), 50.0f);
        const float lf = floorf(b);
        const float f  = b - lf;
        const int  li  = (int)lf;
        while (li > cur) {                       // advances at most 1 (step c < 1)
            sb[ib + cur] = vcur;
            vcur = vnext; vnext = 0.0f; ++cur;
        }
        vcur  = fmaf(1.0f - f, p[j], vcur);
        vnext = fmaf(f,        p[j], vnext);
    }
    sb[ib + cur] = vcur;
    if (cur < ATOMS - 1) sb[ib + cur + 1] = vnext;
}

__global__ __launch_bounds__(THREADS) void c51_project(
    const float* __restrict__ prob,
    const float* __restrict__ rin,
    const float* __restrict__ done,
    float* __restrict__ out,
    int nrows)
{
    __shared__ __align__(16) float s_buf[2 * TILE_FLOATS];
    const int t = threadIdx.x;
    const int G = gridDim.x;
    const int ntiles = nrows / RPB;
    const int tail_rows = nrows - ntiles * RPB;

    int tk = blockIdx.x;
    if (tk < ntiles) {
        // prologue: stage tile tk into buf0, prefetch its r/done
        stage_tile(prob + (size_t)tk * TILE_FLOATS, s_buf, t);
        float rv = rin[(size_t)tk * RPB + t];
        float dv = done[(size_t)tk * RPB + t];
        int buf = 0;

        for (; tk < ntiles; tk += G) {
            const int nxt = tk + G;
            float rnx = 0.0f, dnx = 0.0f;
            if (nxt < ntiles) {
                stage_tile(prob + (size_t)nxt * TILE_FLOATS,
                           s_buf + (buf ^ 1) * TILE_FLOATS, t);
                rnx = rin[(size_t)nxt * RPB + t];
                dnx = done[(size_t)nxt * RPB + t];
                asm volatile("s_waitcnt vmcnt(15)" ::: "memory");
            } else {
                asm volatile("s_waitcnt vmcnt(0)" ::: "memory");
            }
            __builtin_amdgcn_sched_barrier(0);

            float* sb = s_buf + buf * TILE_FLOATS;
            compute_row(sb, t, rv, dv);

            // coalesced float4 writeout (ds_read_b128 + global_store_dwordx4)
            float4* dst = reinterpret_cast<float4*>(out + (size_t)tk * TILE_FLOATS);
            const float4* sv = reinterpret_cast<const float4*>(sb);
            #pragma unroll
            for (int i = 0; i < STAGE_ITERS; ++i) {
                const int v = i * THREADS + t;
                if (v < TILE_VECS) dst[v] = sv[v];
            }

            rv = rnx; dv = dnx;
            buf ^= 1;
        }
    }

    // ---- tail tile (nrows % 64), plain-HIP path, block 0 only ----
    if (tail_rows > 0 && blockIdx.x == 0) {
        const long long row0 = (long long)ntiles * RPB;
        const int n_e = tail_rows * ATOMS;
        const float* gsrc = prob + (size_t)row0 * ATOMS;
        for (int e = t; e < n_e; e += THREADS) s_buf[e] = gsrc[e];
        __syncthreads();
        if (t < tail_rows) compute_row(s_buf, t, rin[row0 + t], done[row0 + t]);
        __syncthreads();
        float* dst = out + (size_t)row0 * ATOMS;
        for (int e = t; e < n_e; e += THREADS) dst[e] = s_buf[e];
    }
}

extern "C" void kernel_launch(void* const* d_in, const int* in_sizes, int n_in,
                              void* d_out, int out_size, void* d_ws, size_t ws_size,
                              hipStream_t stream) {
    const float* prob = (const float*)d_in[0];
    const float* r    = (const float*)d_in[1];
    const float* done = (const float*)d_in[2];
    float* outp = (float*)d_out;
    const int B = in_sizes[1];               // r: [B,1]
    const int ntiles = B / RPB;
    int grid = ntiles < GRID_MAX ? ntiles : GRID_MAX;
    if (grid < 1) grid = 1;                  // tail-only case
    c51_project<<<dim3(grid), dim3(THREADS), 0, stream>>>(prob, r, done, outp, B);
}

// Round 4
// 41.000 us; speedup vs baseline: 7.1540x; 1.1558x over previous
//
#include <hip/hip_runtime.h>
#include <stdint.h>

// C51 categorical projection — reg-staged pipeline, single LDS buffer.
//
// R3 lesson: LDS double-buffer (26KB/wave) capped occupancy at 6 waves/CU and
// canceled the prefetch gain (R2 12-wave no-prefetch == R3 6-wave prefetch ==
// ~48us). This version keeps the 13KB single buffer (12 waves/CU) and stages
// the NEXT tile into registers (T14 async-split): loads issue right after the
// current tile's LDS handoff, and their vmcnt wait (compiler-inserted at the
// reg->LDS write next iteration) lands after a full compute+writeout phase.
//
// Single-wave blocks: DS pipe is in-order per wave, so the read-p / zero /
// emit / writeout-read / stage-write sequence over the same LDS needs no
// barrier and no manual lgkmcnt.
//
// Per iter k (stage regs hold tile k's data on entry):
//   1. ds_write_b128 x13: stage regs -> LDS     (compiler waits vmcnt here)
//   2. issue global_load_dwordx4 x13 + r/done   (tile k+1 -> regs)
//   3. p[51] <- LDS (51 ds_read_b32, 2-way bank-free: 51 mod 32 = 19)
//   4. zero tile flat (13 ds_write_b128)        (in-order after step-3 reads)
//   5. stream-emit bins into LDS (monotone l_j, no atomics)
//   6. writeout: 13 x (ds_read_b128 -> global_store_dwordx4)

#define ATOMS 51
#define RPB   64
#define THREADS 64
#define TILE_FLOATS (RPB * ATOMS)          // 3264 floats = 13056 B
#define TILE_VECS   (TILE_FLOATS / 4)      // 816
#define VEC_ITERS   ((TILE_VECS + THREADS - 1) / THREADS)  // 13 (last iter: 48 lanes)
#define GRID_MAX 3072                      // 256 CU x 12 blocks (LDS-capped)

__device__ __forceinline__ void compute_row(float* sb, int t, float rr, float dn) {
    const float c = 0.9f * (1.0f - dn);                      // exactly 0.9 or 0.0
    const float base = fmaf(-16.66666667f, c, (rr + 40.0f) * (1.0f / 2.4f));
    const int ib = t * ATOMS;

    // ---- read own row into regs (static unroll; 2-way bank aliasing = free) ----
    float p[ATOMS];
    #pragma unroll
    for (int j = 0; j < ATOMS; ++j) p[j] = sb[ib + j];

    // ---- zero whole tile, flat b128 (all 51 reads above issue first; DS pipe
    //      is in-order within the wave -> no race) ----
    {
        float4* sv = reinterpret_cast<float4*>(sb);
        const float4 z = make_float4(0.f, 0.f, 0.f, 0.f);
        #pragma unroll
        for (int i = 0; i < VEC_ITERS; ++i) {
            const int v = i * THREADS + t;
            if (v < TILE_VECS) sv[v] = z;
        }
    }

    // ---- scatter-free streaming emit (monotone: l_j advances by 0 or 1) ----
    int   cur  = (int)floorf(fminf(fmaxf(base, 0.0f), 50.0f));
    float vcur = 0.0f, vnext = 0.0f;
    #pragma unroll
    for (int j = 0; j < ATOMS; ++j) {
        float b = fmaf(c, (float)j, base);
        b = fminf(fmaxf(b, 0.0f), 50.0f);
        const float lf = floorf(b);
        const float f  = b - lf;
        const int  li  = (int)lf;
        if (li > cur) {                          // at most 1 step (c < 1)
            sb[ib + cur] = vcur;
            vcur = vnext; vnext = 0.0f; ++cur;
        }
        vcur  = fmaf(1.0f - f, p[j], vcur);
        vnext = fmaf(f,        p[j], vnext);
    }
    sb[ib + cur] = vcur;
    if (cur < ATOMS - 1) sb[ib + cur + 1] = vnext;
}

__global__ __launch_bounds__(THREADS) void c51_project(
    const float* __restrict__ prob,
    const float* __restrict__ rin,
    const float* __restrict__ done,
    float* __restrict__ out,
    int nrows)
{
    __shared__ __align__(16) float s_buf[TILE_FLOATS];
    const int t = threadIdx.x;
    const int G = gridDim.x;
    const int ntiles = nrows / RPB;
    const int tail_rows = nrows - ntiles * RPB;

    int tk = blockIdx.x;
    if (tk < ntiles) {
        // ---- prologue: load tile tk + its r/done into regs ----
        float4 stg[VEC_ITERS];
        {
            const float4* gsrc = reinterpret_cast<const float4*>(prob + (size_t)tk * TILE_FLOATS);
            #pragma unroll
            for (int i = 0; i < VEC_ITERS; ++i) {
                const int v = i * THREADS + t;
                stg[i] = (v < TILE_VECS) ? gsrc[v] : make_float4(0.f, 0.f, 0.f, 0.f);
            }
        }
        float rv = rin[(size_t)tk * RPB + t];
        float dv = done[(size_t)tk * RPB + t];

        for (; tk < ntiles; tk += G) {
            // 1. hand staged regs to LDS (compiler inserts the vmcnt wait)
            {
                float4* sv = reinterpret_cast<float4*>(s_buf);
                #pragma unroll
                for (int i = 0; i < VEC_ITERS; ++i) {
                    const int v = i * THREADS + t;
                    if (v < TILE_VECS) sv[v] = stg[i];
                }
            }

            // 2. issue next tile's loads early (latency hides under compute)
            const int nxt = tk + G;
            float rnx = 0.0f, dnx = 0.0f;
            if (nxt < ntiles) {
                const float4* gsrc = reinterpret_cast<const float4*>(prob + (size_t)nxt * TILE_FLOATS);
                #pragma unroll
                for (int i = 0; i < VEC_ITERS; ++i) {
                    const int v = i * THREADS + t;
                    if (v < TILE_VECS) stg[i] = gsrc[v];
                }
                rnx = rin[(size_t)nxt * RPB + t];
                dnx = done[(size_t)nxt * RPB + t];
            }
            __builtin_amdgcn_sched_barrier(0);   // keep loads hoisted above compute

            // 3-5. compute (reads row, zeroes tile, streams bins back)
            compute_row(s_buf, t, rv, dv);

            // 6. coalesced writeout
            {
                float4* dst = reinterpret_cast<float4*>(out + (size_t)tk * TILE_FLOATS);
                const float4* sv = reinterpret_cast<const float4*>(s_buf);
                #pragma unroll
                for (int i = 0; i < VEC_ITERS; ++i) {
                    const int v = i * THREADS + t;
                    if (v < TILE_VECS) dst[v] = sv[v];
                }
            }

            rv = rnx; dv = dnx;
        }
    }

    // ---- tail tile (nrows % 64) — block 0, plain path ----
    if (tail_rows > 0 && blockIdx.x == 0) {
        const long long row0 = (long long)ntiles * RPB;
        const int n_e = tail_rows * ATOMS;
        const float* gsrc = prob + (size_t)row0 * ATOMS;
        __syncthreads();
        for (int e = t; e < n_e; e += THREADS) s_buf[e] = gsrc[e];
        __syncthreads();
        if (t < tail_rows) compute_row(s_buf, t, rin[row0 + t], done[row0 + t]);
        __syncthreads();
        float* dst = out + (size_t)row0 * ATOMS;
        for (int e = t; e < n_e; e += THREADS) dst[e] = s_buf[e];
    }
}

extern "C" void kernel_launch(void* const* d_in, const int* in_sizes, int n_in,
                              void* d_out, int out_size, void* d_ws, size_t ws_size,
                              hipStream_t stream) {
    const float* prob = (const float*)d_in[0];
    const float* r    = (const float*)d_in[1];
    const float* done = (const float*)d_in[2];
    float* outp = (float*)d_out;
    const int B = in_sizes[1];               // r: [B,1]
    const int ntiles = B / RPB;
    int grid = ntiles < GRID_MAX ? ntiles : GRID_MAX;
    if (grid < 1) grid = 1;
    c51_project<<<dim3(grid), dim3(THREADS), 0, stream>>>(prob, r, done, outp, B);
}

// Round 5
// 40.653 us; speedup vs baseline: 7.2152x; 1.0086x over previous
//
#include <hip/hip_runtime.h>
#include <stdint.h>

// C51 categorical projection — reg-staged pipeline, single LDS buffer,
// balanced 4-deep grid-stride.
//
// R4 lesson: at GRID=3072 each block ran 2.67 iters -> ~37% of tiles carry an
// exposed prologue (cold 13KB load with nothing to hide under) + 3-vs-2 tile
// imbalance dependent on undefined block->CU placement. GRID=2048 gives every
// block exactly 4 tiles (8192/2048), fill/drain 25%, 8 blocks/CU (2 waves/SIMD,
// 104KB LDS in-flight >> 9KB latency-BW product).
//
// Structure per iter k (stage regs hold tile k's data on entry):
//   1. ds_write_b128 x13: stage regs -> LDS     (compiler waits vmcnt here)
//   2. issue global_load_dwordx4 x13 + r/done   (tile k+1 -> regs)
//   3. p[51] <- LDS (51 ds_read_b32, 2-way bank aliasing = free: 51*t mod 32
//      has gcd(19,32)=1)
//   4. zero tile flat (13 ds_write_b128; in-order DS pipe after step-3 reads)
//   5. stream-emit bins into LDS (monotone l_j, scatter-free, no atomics)
//   6. writeout: 13 x (ds_read_b128 -> global_store_dwordx4)
// Single-wave blocks: DS pipe is in-order per wave -> no barriers anywhere.

#define ATOMS 51
#define RPB   64
#define THREADS 64
#define TILE_FLOATS (RPB * ATOMS)          // 3264 floats = 13056 B
#define TILE_VECS   (TILE_FLOATS / 4)      // 816
#define VEC_ITERS   ((TILE_VECS + THREADS - 1) / THREADS)  // 13 (last iter: 48 lanes)
#define GRID_MAX 2048                      // 8192 tiles / 2048 = exactly 4 iters/block

__device__ __forceinline__ void compute_row(float* sb, int t, float rr, float dn) {
    const float c = 0.9f * (1.0f - dn);                      // exactly 0.9 or 0.0
    const float base = fmaf(-16.66666667f, c, (rr + 40.0f) * (1.0f / 2.4f));
    const int ib = t * ATOMS;

    // ---- read own row into regs (compiler interleaves into the j-loop) ----
    float p[ATOMS];
    #pragma unroll
    for (int j = 0; j < ATOMS; ++j) p[j] = sb[ib + j];

    // ---- zero whole tile, flat b128 (13 uniform issues beats divergent
    //      range-zeroing: done-lanes make zero spans wave-wide ~55 trips) ----
    {
        float4* sv = reinterpret_cast<float4*>(sb);
        const float4 z = make_float4(0.f, 0.f, 0.f, 0.f);
        #pragma unroll
        for (int i = 0; i < VEC_ITERS; ++i) {
            const int v = i * THREADS + t;
            if (v < TILE_VECS) sv[v] = z;
        }
    }

    // ---- scatter-free streaming emit (l_j advances by 0 or 1; c < 1) ----
    int   cur  = (int)floorf(fminf(fmaxf(base, 0.0f), 50.0f));
    float vcur = 0.0f, vnext = 0.0f;
    #pragma unroll
    for (int j = 0; j < ATOMS; ++j) {
        float b = fmaf(c, (float)j, base);
        b = fminf(fmaxf(b, 0.0f), 50.0f);
        const float lf = floorf(b);
        const float f  = b - lf;
        const int  li  = (int)lf;
        if (li > cur) {
            sb[ib + cur] = vcur;
            vcur = vnext; vnext = 0.0f; ++cur;
        }
        vcur  = fmaf(1.0f - f, p[j], vcur);
        vnext = fmaf(f,        p[j], vnext);
    }
    sb[ib + cur] = vcur;
    if (cur < ATOMS - 1) sb[ib + cur + 1] = vnext;
}

__global__ __launch_bounds__(THREADS) void c51_project(
    const float* __restrict__ prob,
    const float* __restrict__ rin,
    const float* __restrict__ done,
    float* __restrict__ out,
    int nrows)
{
    __shared__ __align__(16) float s_buf[TILE_FLOATS];
    const int t = threadIdx.x;
    const int G = gridDim.x;
    const int ntiles = nrows / RPB;
    const int tail_rows = nrows - ntiles * RPB;

    int tk = blockIdx.x;
    if (tk < ntiles) {
        // ---- prologue: load tile tk + its r/done into regs ----
        float4 stg[VEC_ITERS];
        {
            const float4* gsrc = reinterpret_cast<const float4*>(prob + (size_t)tk * TILE_FLOATS);
            #pragma unroll
            for (int i = 0; i < VEC_ITERS; ++i) {
                const int v = i * THREADS + t;
                stg[i] = (v < TILE_VECS) ? gsrc[v] : make_float4(0.f, 0.f, 0.f, 0.f);
            }
        }
        float rv = rin[(size_t)tk * RPB + t];
        float dv = done[(size_t)tk * RPB + t];

        for (; tk < ntiles; tk += G) {
            // 1. hand staged regs to LDS (compiler inserts the vmcnt wait)
            {
                float4* sv = reinterpret_cast<float4*>(s_buf);
                #pragma unroll
                for (int i = 0; i < VEC_ITERS; ++i) {
                    const int v = i * THREADS + t;
                    if (v < TILE_VECS) sv[v] = stg[i];
                }
            }

            // 2. issue next tile's loads early (latency hides under compute)
            const int nxt = tk + G;
            float rnx = 0.0f, dnx = 0.0f;
            if (nxt < ntiles) {
                const float4* gsrc = reinterpret_cast<const float4*>(prob + (size_t)nxt * TILE_FLOATS);
                #pragma unroll
                for (int i = 0; i < VEC_ITERS; ++i) {
                    const int v = i * THREADS + t;
                    if (v < TILE_VECS) stg[i] = gsrc[v];
                }
                rnx = rin[(size_t)nxt * RPB + t];
                dnx = done[(size_t)nxt * RPB + t];
            }
            __builtin_amdgcn_sched_barrier(0);   // keep loads hoisted above compute

            // 3-5. compute (reads row, zeroes tile, streams bins back)
            compute_row(s_buf, t, rv, dv);

            // 6. coalesced writeout
            {
                float4* dst = reinterpret_cast<float4*>(out + (size_t)tk * TILE_FLOATS);
                const float4* sv = reinterpret_cast<const float4*>(s_buf);
                #pragma unroll
                for (int i = 0; i < VEC_ITERS; ++i) {
                    const int v = i * THREADS + t;
                    if (v < TILE_VECS) dst[v] = sv[v];
                }
            }

            rv = rnx; dv = dnx;
        }
    }

    // ---- tail tile (nrows % 64) — block 0, plain path ----
    if (tail_rows > 0 && blockIdx.x == 0) {
        const long long row0 = (long long)ntiles * RPB;
        const int n_e = tail_rows * ATOMS;
        const float* gsrc = prob + (size_t)row0 * ATOMS;
        __syncthreads();
        for (int e = t; e < n_e; e += THREADS) s_buf[e] = gsrc[e];
        __syncthreads();
        if (t < tail_rows) compute_row(s_buf, t, rin[row0 + t], done[row0 + t]);
        __syncthreads();
        float* dst = out + (size_t)row0 * ATOMS;
        for (int e = t; e < n_e; e += THREADS) dst[e] = s_buf[e];
    }
}

extern "C" void kernel_launch(void* const* d_in, const int* in_sizes, int n_in,
                              void* d_out, int out_size, void* d_ws, size_t ws_size,
                              hipStream_t stream) {
    const float* prob = (const float*)d_in[0];
    const float* r    = (const float*)d_in[1];
    const float* done = (const float*)d_in[2];
    float* outp = (float*)d_out;
    const int B = in_sizes[1];               // r: [B,1]
    const int ntiles = B / RPB;
    int grid = ntiles < GRID_MAX ? ntiles : GRID_MAX;
    if (grid < 1) grid = 1;
    c51_project<<<dim3(grid), dim3(THREADS), 0, stream>>>(prob, r, done, outp, B);
}

// Round 7
// 40.368 us; speedup vs baseline: 7.2660x; 1.0070x over previous
//
#include <hip/hip_runtime.h>
#include <stdint.h>

// C51 categorical projection — reg-staged pipeline, single LDS buffer,
// non-temporal writeout.
//
// R5 insight: working set prob(107MB)+out(107MB)+r/done(4MB) = 218MB < 256MB
// L3, yet FETCH=54MB/dispatch — the out WRITE stream (zero kernel-side reuse)
// thrashes L3 and evicts half of prob every replay. Single change vs R5:
// writeout uses __builtin_nontemporal_store (nt global_store_dwordx4,
// streaming MTYPE, no L3 allocation) so L3 capacity goes entirely to prob.
// R6 lesson: the builtin rejects HIP_vector_type structs — use a clang
// ext_vector float4 alias (same 16B layout).
//
// Structure per iter k (stage regs hold tile k's data on entry):
//   1. ds_write_b128 x13: stage regs -> LDS     (compiler waits vmcnt here)
//   2. issue global_load_dwordx4 x13 + r/done   (tile k+1 -> regs)
//   3. p[51] <- LDS (51 ds_read_b32; 2-way bank aliasing = free)
//   4. zero tile flat (13 ds_write_b128; DS pipe in-order after step-3 reads)
//   5. stream-emit bins into LDS (monotone l_j, scatter-free, no atomics)
//   6. writeout: 13 x (ds_read_b128 -> nt global_store_dwordx4)
// Single-wave blocks: DS pipe in-order per wave -> no barriers anywhere.

#define ATOMS 51
#define RPB   64
#define THREADS 64
#define TILE_FLOATS (RPB * ATOMS)          // 3264 floats = 13056 B
#define TILE_VECS   (TILE_FLOATS / 4)      // 816
#define VEC_ITERS   ((TILE_VECS + THREADS - 1) / THREADS)  // 13 (last iter: 48 lanes)
#define GRID_MAX 2048                      // 8192 tiles / 2048 = exactly 4 iters/block

typedef float vfloat4 __attribute__((ext_vector_type(4)));  // native vec for nt builtin

__device__ __forceinline__ void compute_row(float* sb, int t, float rr, float dn) {
    const float c = 0.9f * (1.0f - dn);                      // exactly 0.9 or 0.0
    const float base = fmaf(-16.66666667f, c, (rr + 40.0f) * (1.0f / 2.4f));
    const int ib = t * ATOMS;

    // ---- read own row into regs (compiler interleaves into the j-loop) ----
    float p[ATOMS];
    #pragma unroll
    for (int j = 0; j < ATOMS; ++j) p[j] = sb[ib + j];

    // ---- zero whole tile, flat b128 ----
    {
        vfloat4* sv = reinterpret_cast<vfloat4*>(sb);
        const vfloat4 z = {0.f, 0.f, 0.f, 0.f};
        #pragma unroll
        for (int i = 0; i < VEC_ITERS; ++i) {
            const int v = i * THREADS + t;
            if (v < TILE_VECS) sv[v] = z;
        }
    }

    // ---- scatter-free streaming emit (l_j advances by 0 or 1; c < 1) ----
    int   cur  = (int)floorf(fminf(fmaxf(base, 0.0f), 50.0f));
    float vcur = 0.0f, vnext = 0.0f;
    #pragma unroll
    for (int j = 0; j < ATOMS; ++j) {
        float b = fmaf(c, (float)j, base);
        b = fminf(fmaxf(b, 0.0f), 50.0f);
        const float lf = floorf(b);
        const float f  = b - lf;
        const int  li  = (int)lf;
        if (li > cur) {
            sb[ib + cur] = vcur;
            vcur = vnext; vnext = 0.0f; ++cur;
        }
        vcur  = fmaf(1.0f - f, p[j], vcur);
        vnext = fmaf(f,        p[j], vnext);
    }
    sb[ib + cur] = vcur;
    if (cur < ATOMS - 1) sb[ib + cur + 1] = vnext;
}

__global__ __launch_bounds__(THREADS) void c51_project(
    const float* __restrict__ prob,
    const float* __restrict__ rin,
    const float* __restrict__ done,
    float* __restrict__ out,
    int nrows)
{
    __shared__ __align__(16) float s_buf[TILE_FLOATS];
    const int t = threadIdx.x;
    const int G = gridDim.x;
    const int ntiles = nrows / RPB;
    const int tail_rows = nrows - ntiles * RPB;

    int tk = blockIdx.x;
    if (tk < ntiles) {
        // ---- prologue: load tile tk + its r/done into regs ----
        vfloat4 stg[VEC_ITERS];
        {
            const vfloat4* gsrc = reinterpret_cast<const vfloat4*>(prob + (size_t)tk * TILE_FLOATS);
            #pragma unroll
            for (int i = 0; i < VEC_ITERS; ++i) {
                const int v = i * THREADS + t;
                stg[i] = (v < TILE_VECS) ? gsrc[v] : (vfloat4){0.f, 0.f, 0.f, 0.f};
            }
        }
        float rv = rin[(size_t)tk * RPB + t];
        float dv = done[(size_t)tk * RPB + t];

        for (; tk < ntiles; tk += G) {
            // 1. hand staged regs to LDS (compiler inserts the vmcnt wait)
            {
                vfloat4* sv = reinterpret_cast<vfloat4*>(s_buf);
                #pragma unroll
                for (int i = 0; i < VEC_ITERS; ++i) {
                    const int v = i * THREADS + t;
                    if (v < TILE_VECS) sv[v] = stg[i];
                }
            }

            // 2. issue next tile's loads early (latency hides under compute)
            const int nxt = tk + G;
            float rnx = 0.0f, dnx = 0.0f;
            if (nxt < ntiles) {
                const vfloat4* gsrc = reinterpret_cast<const vfloat4*>(prob + (size_t)nxt * TILE_FLOATS);
                #pragma unroll
                for (int i = 0; i < VEC_ITERS; ++i) {
                    const int v = i * THREADS + t;
                    if (v < TILE_VECS) stg[i] = gsrc[v];
                }
                rnx = rin[(size_t)nxt * RPB + t];
                dnx = done[(size_t)nxt * RPB + t];
            }
            __builtin_amdgcn_sched_barrier(0);   // keep loads hoisted above compute

            // 3-5. compute (reads row, zeroes tile, streams bins back)
            compute_row(s_buf, t, rv, dv);

            // 6. coalesced writeout — NON-TEMPORAL: out has no kernel-side
            //    reuse; don't let 107MB/dispatch of dirty lines evict prob
            //    from L3 (R5: that thrash cost 54MB/dispatch of HBM re-fetch)
            {
                vfloat4* dst = reinterpret_cast<vfloat4*>(out + (size_t)tk * TILE_FLOATS);
                const vfloat4* sv = reinterpret_cast<const vfloat4*>(s_buf);
                #pragma unroll
                for (int i = 0; i < VEC_ITERS; ++i) {
                    const int v = i * THREADS + t;
                    if (v < TILE_VECS) __builtin_nontemporal_store(sv[v], &dst[v]);
                }
            }

            rv = rnx; dv = dnx;
        }
    }

    // ---- tail tile (nrows % 64) — block 0, plain path ----
    if (tail_rows > 0 && blockIdx.x == 0) {
        const long long row0 = (long long)ntiles * RPB;
        const int n_e = tail_rows * ATOMS;
        const float* gsrc = prob + (size_t)row0 * ATOMS;
        __syncthreads();
        for (int e = t; e < n_e; e += THREADS) s_buf[e] = gsrc[e];
        __syncthreads();
        if (t < tail_rows) compute_row(s_buf, t, rin[row0 + t], done[row0 + t]);
        __syncthreads();
        float* dst = out + (size_t)row0 * ATOMS;
        for (int e = t; e < n_e; e += THREADS) dst[e] = s_buf[e];
    }
}

extern "C" void kernel_launch(void* const* d_in, const int* in_sizes, int n_in,
                              void* d_out, int out_size, void* d_ws, size_t ws_size,
                              hipStream_t stream) {
    const float* prob = (const float*)d_in[0];
    const float* r    = (const float*)d_in[1];
    const float* done = (const float*)d_in[2];
    float* outp = (float*)d_out;
    const int B = in_sizes[1];               // r: [B,1]
    const int ntiles = B / RPB;
    int grid = ntiles < GRID_MAX ? ntiles : GRID_MAX;
    if (grid < 1) grid = 1;
    c51_project<<<dim3(grid), dim3(THREADS), 0, stream>>>(prob, r, done, outp, B);
}